// Round 14
// baseline (59.886 us; speedup 1.0000x reference)
//
#include <hip/hip_runtime.h>
#include <math.h>

#define D 40
#define NN 1024
#define BB 2
#define SPB 4            // 256-j spans per row (max)
#define PSTR 44          // floats per partial slot: o[40], l, pad

typedef __attribute__((ext_vector_type(8))) _Float16 f16x8;
typedef __attribute__((ext_vector_type(4))) float f32x4;

__device__ __forceinline__ unsigned int pk16(float a, float b) {
    return __builtin_bit_cast(unsigned int, __builtin_amdgcn_cvt_pkrtz(a, b));
}

// gelu = a - a/(exp2(a*(c1*a^2+c0))+1); 5 VALU + 2 trans
__device__ __forceinline__ float gelu_tanh(float a) {
    float u = a * a;
    float t1 = fmaf(0.10294366f, u, 2.3022083f);
    float e = __builtin_amdgcn_exp2f(a * t1);
    float r = __builtin_amdgcn_rcpf(e + 1.0f);
    return fmaf(-a, r, a);
}

// anti-remat pins
__device__ __forceinline__ void pinf(float& x) { asm volatile("" : "+v"(x)); }
__device__ __forceinline__ void pin4(float4& v) {
    asm volatile("" : "+v"(v.x), "+v"(v.y), "+v"(v.z), "+v"(v.w));
}
__device__ __forceinline__ void pin8(f16x8& v) {
    uint4 u = __builtin_bit_cast(uint4, v);
    asm volatile("" : "+v"(u.x), "+v"(u.y), "+v"(u.z), "+v"(u.w));
    v = __builtin_bit_cast(f16x8, u);
}

// build fp16x8 B-fragment: gelu(air + ajv) for 8 consecutive k
__device__ __forceinline__ f16x8 frag8(float4 a0, float4 a1, float4 x0, float4 x1) {
    float g0 = gelu_tanh(a0.x + x0.x);
    float g1 = gelu_tanh(a0.y + x0.y);
    float g2 = gelu_tanh(a0.z + x0.z);
    float g3 = gelu_tanh(a0.w + x0.w);
    float g4 = gelu_tanh(a1.x + x1.x);
    float g5 = gelu_tanh(a1.y + x1.y);
    float g6 = gelu_tanh(a1.z + x1.z);
    float g7 = gelu_tanh(a1.w + x1.w);
    return __builtin_bit_cast(f16x8,
        make_uint4(pk16(g0, g1), pk16(g2, g3), pk16(g4, g5), pk16(g6, g7)));
}

// ai = x @ W1[:D] + b1, aj = x @ W1[D:].  2 rows/block; one 40-FMA chain/thread.
__global__ __launch_bounds__(256) void precompute_kernel(
    const float* __restrict__ x, const float* __restrict__ W1,
    const float* __restrict__ b1, const float* __restrict__ W2,
    float* __restrict__ ai, float* __restrict__ aj, uint4* __restrict__ w2fT) {
    const int t = threadIdx.x;
    const int bid = blockIdx.x;
    const int r = (bid << 1) + (t >> 7);
    const int tl = t & 127;
    const float* xr = x + (size_t)r * D;

    if (tl < D) {
        const int d = tl;
        float s = b1[d];
#pragma unroll
        for (int k = 0; k < D; ++k) s = fmaf(xr[k], W1[k * D + d], s);
        ai[(size_t)r * D + d] = s;
    } else if (tl >= 64 && tl < 64 + D) {
        const int d = tl - 64;
        float s = 0.0f;
#pragma unroll
        for (int k = 0; k < D; ++k) s = fmaf(xr[k], W1[(D + k) * D + d], s);
        aj[(size_t)r * D + d] = s;
    }

    if (bid == 0 && t < 64) {
        // A = W2^T: A[m=d, k] = W2[k][d]; lane: m = l&15, k = kt*32 + (l>>4)*8 + e
        const int lr = t & 15, lg = t >> 4;
#pragma unroll
        for (int mt = 0; mt < 3; ++mt)
#pragma unroll
            for (int kt = 0; kt < 2; ++kt) {
                unsigned int u[4];
#pragma unroll
                for (int pe = 0; pe < 4; ++pe) {
                    int k0 = kt * 32 + lg * 8 + pe * 2;
                    int dd = mt * 16 + lr;
                    float v0 = (k0 < D && dd < D) ? W2[k0 * D + dd] : 0.0f;
                    float v1 = (k0 + 1 < D && dd < D) ? W2[(k0 + 1) * D + dd] : 0.0f;
                    u[pe] = pk16(v0, v1);
                }
                w2fT[(mt * 2 + kt) * 64 + t] = make_uint4(u[0], u[1], u[2], u[3]);
            }
    }
}

// One block per (bb, row, 256-j span). Blocks past the diagonal exit at once.
// Partial (sum e^s * p, sum e^s) -> slot [(bb*NN+i)*SPB + span].
__global__ __launch_bounds__(256)
__attribute__((amdgpu_waves_per_eu(4)))
void pair_span_kernel(
    const float* __restrict__ ai_g, const float* __restrict__ aj_g,
    const uint4* __restrict__ w2fT, const float* __restrict__ b2,
    float* __restrict__ partial) {
    const int bid = blockIdx.x;
    const int sp = bid >> 11;                 // 0..3
    const int bb = bid & 1;
    const int i = NN - 1 - ((bid >> 1) & (NN - 1));   // big rows first
    const int sbase = sp << 8;
    if (sbase > i) return;                    // empty span

    __shared__ float mbuf[224];               // 4 waves x 56

    const int t = threadIdx.x;
    const int wv = t >> 6;
    const int l = t & 63;
    const int lr = l & 15;
    const int lg = l >> 4;
    const int idxA = lr << 2;

    // W2^T A-fragments (zero rows for k>=40 kill don't-care B slots), pinned
    f16x8 w2t[3][2];
#pragma unroll
    for (int mt = 0; mt < 3; ++mt)
#pragma unroll
        for (int kt = 0; kt < 2; ++kt) {
            w2t[mt][kt] = __builtin_bit_cast(f16x8, w2fT[(mt * 2 + kt) * 64 + l]);
            pin8(w2t[mt][kt]);
        }

    float bv2[3][4];
#pragma unroll
    for (int mt = 0; mt < 3; ++mt)
#pragma unroll
        for (int r = 0; r < 4; ++r) {
            int d = mt * 16 + lg * 4 + r;
            bv2[mt][r] = (d < D) ? b2[d] : 0.0f;
            pinf(bv2[mt][r]);
        }

    const float* ai_row = ai_g + ((size_t)bb * NN + i) * D;
    float4 air0 = *reinterpret_cast<const float4*>(ai_row + (lg << 3));
    float4 air1 = *reinterpret_cast<const float4*>(ai_row + (lg << 3) + 4);
    float4 ai32 = *reinterpret_cast<const float4*>(ai_row + 32 + ((l >> 5) << 2));
    pin4(air0); pin4(air1); pin4(ai32);

    const float* aj_b = aj_g + (size_t)bb * NN * D;

    float l_run = 0.0f;
    float o[3][4];
#pragma unroll
    for (int mt = 0; mt < 3; ++mt)
#pragma unroll
        for (int r = 0; r < 4; ++r) o[mt][r] = 0.0f;

    auto window = [&](int jb, float4 qa0, float4 qa1, float4 qb0,
                      float4 qb1, float4 qt, bool masked) {
        // tail gelu: k = 32+kk..+3 (kk=(l>>5)*4) of j = jb+(l&31)
        unsigned int pd0, pd1;
        {
            float g0 = gelu_tanh(ai32.x + qt.x);
            float g1 = gelu_tanh(ai32.y + qt.y);
            float g2 = gelu_tanh(ai32.z + qt.z);
            float g3 = gelu_tanh(ai32.w + qt.w);
            pd0 = pk16(g0, g1);
            pd1 = pk16(g2, g3);
        }
        uint4 tB0, tB1;
        tB0.x = __builtin_amdgcn_ds_bpermute(idxA,       pd0);
        tB0.y = __builtin_amdgcn_ds_bpermute(idxA,       pd1);
        tB0.z = __builtin_amdgcn_ds_bpermute(idxA + 128, pd0);
        tB0.w = __builtin_amdgcn_ds_bpermute(idxA + 128, pd1);
        tB1.x = __builtin_amdgcn_ds_bpermute(idxA + 64,  pd0);
        tB1.y = __builtin_amdgcn_ds_bpermute(idxA + 64,  pd1);
        tB1.z = __builtin_amdgcn_ds_bpermute(idxA + 192, pd0);
        tB1.w = __builtin_amdgcn_ds_bpermute(idxA + 192, pd1);

        f32x4 acc[3][2];
#pragma unroll
        for (int mt = 0; mt < 3; ++mt)
#pragma unroll
            for (int n = 0; n < 2; ++n)
                acc[mt][n] = (f32x4){bv2[mt][0], bv2[mt][1], bv2[mt][2], bv2[mt][3]};
        {
            f16x8 B = frag8(air0, air1, qa0, qa1);
            f16x8 Bt = __builtin_bit_cast(f16x8, tB0);
#pragma unroll
            for (int mt = 0; mt < 3; ++mt) {
                acc[mt][0] = __builtin_amdgcn_mfma_f32_16x16x32_f16(
                    w2t[mt][0], B, acc[mt][0], 0, 0, 0);
                acc[mt][0] = __builtin_amdgcn_mfma_f32_16x16x32_f16(
                    w2t[mt][1], Bt, acc[mt][0], 0, 0, 0);
            }
        }
        {
            f16x8 B = frag8(air0, air1, qb0, qb1);
            f16x8 Bt = __builtin_bit_cast(f16x8, tB1);
#pragma unroll
            for (int mt = 0; mt < 3; ++mt) {
                acc[mt][1] = __builtin_amdgcn_mfma_f32_16x16x32_f16(
                    w2t[mt][0], B, acc[mt][1], 0, 0, 0);
                acc[mt][1] = __builtin_amdgcn_mfma_f32_16x16x32_f16(
                    w2t[mt][1], Bt, acc[mt][1], 0, 0, 0);
            }
        }

        // ||p|| per j; weights e^s directly (no max shift; validated R13)
        float sv[2];
#pragma unroll
        for (int n = 0; n < 2; ++n) {
            float sq = 0.0f;
#pragma unroll
            for (int mt = 0; mt < 3; ++mt)
#pragma unroll
                for (int r = 0; r < 4; ++r)
                    sq = fmaf(acc[mt][n][r], acc[mt][n][r], sq);
            sq += __shfl_xor(sq, 16);
            sq += __shfl_xor(sq, 32);
            if (masked) {
                int j = jb + n * 16 + lr;
                sv[n] = (j <= i) ? __builtin_amdgcn_sqrtf(sq) : -1e30f;
            } else {
                sv[n] = __builtin_amdgcn_sqrtf(sq);
            }
        }
        float w0 = __expf(sv[0]);              // masked j -> exactly 0
        float w1 = __expf(sv[1]);
        l_run += w0 + w1;
#pragma unroll
        for (int mt = 0; mt < 3; ++mt)
#pragma unroll
            for (int r = 0; r < 4; ++r)
                o[mt][r] = fmaf(w0, acc[mt][0][r], fmaf(w1, acc[mt][1][r], o[mt][r]));
    };

    // ---- at most 2 windows per wave within this 256-j span ----
#pragma unroll
    for (int q = 0; q < 2; ++q) {
        const int jb = sbase + (q << 7) + (wv << 5);
        if (jb > i) continue;
        const bool masked = (jb + 31 > i);
        float4 qa0, qa1, qb0, qb1, qt;
        if (!masked) {
            const float* r0 = aj_b + (size_t)(jb + lr) * D + (lg << 3);
            qa0 = *reinterpret_cast<const float4*>(r0);
            qa1 = *reinterpret_cast<const float4*>(r0 + 4);
            qb0 = *reinterpret_cast<const float4*>(r0 + 16 * D);
            qb1 = *reinterpret_cast<const float4*>(r0 + 16 * D + 4);
            qt  = *reinterpret_cast<const float4*>(
                aj_b + (size_t)(jb + (l & 31)) * D + 32 + ((l >> 5) << 2));
        } else {
            const int j0 = min(jb + lr, i);
            const int j1 = min(jb + 16 + lr, i);
            const int jt = min(jb + (l & 31), i);
            const float* r0 = aj_b + (size_t)j0 * D + (lg << 3);
            const float* r1 = aj_b + (size_t)j1 * D + (lg << 3);
            qa0 = *reinterpret_cast<const float4*>(r0);
            qa1 = *reinterpret_cast<const float4*>(r0 + 4);
            qb0 = *reinterpret_cast<const float4*>(r1);
            qb1 = *reinterpret_cast<const float4*>(r1 + 4);
            qt  = *reinterpret_cast<const float4*>(
                aj_b + (size_t)jt * D + 32 + ((l >> 5) << 2));
        }
        window(jb, qa0, qa1, qb0, qb1, qt, masked);
    }

    // ---- epilogue: reduce over 16 j-lanes, 4-wave LDS merge, store partial ----
#pragma unroll
    for (int mt = 0; mt < 3; ++mt)
#pragma unroll
        for (int r = 0; r < 4; ++r) {
            float v = o[mt][r];
            v += __shfl_xor(v, 1);
            v += __shfl_xor(v, 2);
            v += __shfl_xor(v, 4);
            v += __shfl_xor(v, 8);
            o[mt][r] = v;
        }
    l_run += __shfl_xor(l_run, 1);
    l_run += __shfl_xor(l_run, 2);
    l_run += __shfl_xor(l_run, 4);
    l_run += __shfl_xor(l_run, 8);

    if (lr == 0) {
#pragma unroll
        for (int mt = 0; mt < 3; ++mt)
#pragma unroll
            for (int r = 0; r < 4; ++r) {
                int d = mt * 16 + lg * 4 + r;
                if (d < D) mbuf[wv * 56 + d] = o[mt][r];
            }
        if (lg == 0) mbuf[wv * 56 + 48] = l_run;
    }
    __syncthreads();
    if (t < 41) {
        const int src = (t < 40) ? t : 48;
        float s = mbuf[src] + mbuf[56 + src] + mbuf[112 + src] + mbuf[168 + src];
        partial[((size_t)((bb << 10) + i) * SPB + sp) * PSTR + t] = s;
    }
}

// out[row,:] = (sum over spans o) / (sum l)
__global__ __launch_bounds__(64) void merge_kernel(
    const float* __restrict__ partial, float* __restrict__ out) {
    const int row = blockIdx.x;                // bb*NN + i
    const int i = row & (NN - 1);
    const int nw = (i >> 8) + 1;
    const int t = threadIdx.x;
    if (t < D) {
        float val = 0.0f, L = 0.0f;
        for (int s = 0; s < nw; ++s) {
            const float* P = partial + ((size_t)row * SPB + s) * PSTR;
            val += P[t];
            L += P[40];
        }
        out[(size_t)row * D + t] = val / L;
    }
}

extern "C" void kernel_launch(void* const* d_in, const int* in_sizes, int n_in,
                              void* d_out, int out_size, void* d_ws, size_t ws_size,
                              hipStream_t stream) {
    const float* x  = (const float*)d_in[0];
    const float* W1 = (const float*)d_in[1];
    const float* b1 = (const float*)d_in[2];
    const float* W2 = (const float*)d_in[3];
    const float* b2 = (const float*)d_in[4];
    float* out = (float*)d_out;

    float* ai = (float*)d_ws;                           // BB*NN*D floats
    float* aj = ai + (size_t)BB * NN * D;               // BB*NN*D floats
    uint4* w2fT = (uint4*)(aj + (size_t)BB * NN * D);   // 384 uint4
    float* partial = (float*)(w2fT + 384);              // BB*NN*SPB*PSTR floats

    precompute_kernel<<<BB * NN / 2, 256, 0, stream>>>(x, W1, b1, W2, ai, aj, w2fT);
    pair_span_kernel<<<BB * NN * SPB, 256, 0, stream>>>(ai, aj, w2fT, b2, partial);
    merge_kernel<<<BB * NN, 64, 0, stream>>>(partial, out);
}

// Round 15
// 37.483 us; speedup vs baseline: 1.5977x; 1.5977x over previous
//
#include <hip/hip_runtime.h>
#include <math.h>

#define D 40
#define NN 1024
#define BB 2

typedef __attribute__((ext_vector_type(8))) _Float16 f16x8;
typedef __attribute__((ext_vector_type(4))) float f32x4;

__device__ __forceinline__ unsigned int pk16(float a, float b) {
    return __builtin_bit_cast(unsigned int, __builtin_amdgcn_cvt_pkrtz(a, b));
}

// gelu = a - a/(exp2(a*(c1*a^2+c0))+1); 5 VALU + 2 trans
__device__ __forceinline__ float gelu_tanh(float a) {
    float u = a * a;
    float t1 = fmaf(0.10294366f, u, 2.3022083f);
    float e = __builtin_amdgcn_exp2f(a * t1);
    float r = __builtin_amdgcn_rcpf(e + 1.0f);
    return fmaf(-a, r, a);
}

// anti-remat pins
__device__ __forceinline__ void pinf(float& x) { asm volatile("" : "+v"(x)); }
__device__ __forceinline__ void pin4(float4& v) {
    asm volatile("" : "+v"(v.x), "+v"(v.y), "+v"(v.z), "+v"(v.w));
}
__device__ __forceinline__ void pin8(f16x8& v) {
    uint4 u = __builtin_bit_cast(uint4, v);
    asm volatile("" : "+v"(u.x), "+v"(u.y), "+v"(u.z), "+v"(u.w));
    v = __builtin_bit_cast(f16x8, u);
}

// build fp16x8 B-fragment: gelu(air + ajv) for 8 consecutive k
__device__ __forceinline__ f16x8 frag8(float4 a0, float4 a1, float4 x0, float4 x1) {
    float g0 = gelu_tanh(a0.x + x0.x);
    float g1 = gelu_tanh(a0.y + x0.y);
    float g2 = gelu_tanh(a0.z + x0.z);
    float g3 = gelu_tanh(a0.w + x0.w);
    float g4 = gelu_tanh(a1.x + x1.x);
    float g5 = gelu_tanh(a1.y + x1.y);
    float g6 = gelu_tanh(a1.z + x1.z);
    float g7 = gelu_tanh(a1.w + x1.w);
    return __builtin_bit_cast(f16x8,
        make_uint4(pk16(g0, g1), pk16(g2, g3), pk16(g4, g5), pk16(g6, g7)));
}

// ai = x @ W1[:D] + b1, aj = x @ W1[D:].  2 rows/block; one 40-FMA chain/thread.
__global__ __launch_bounds__(256) void precompute_kernel(
    const float* __restrict__ x, const float* __restrict__ W1,
    const float* __restrict__ b1, const float* __restrict__ W2,
    float* __restrict__ ai, float* __restrict__ aj, uint4* __restrict__ w2fT) {
    const int t = threadIdx.x;
    const int bid = blockIdx.x;
    const int r = (bid << 1) + (t >> 7);
    const int tl = t & 127;
    const float* xr = x + (size_t)r * D;

    if (tl < D) {
        const int d = tl;
        float s = b1[d];
#pragma unroll
        for (int k = 0; k < D; ++k) s = fmaf(xr[k], W1[k * D + d], s);
        ai[(size_t)r * D + d] = s;
    } else if (tl >= 64 && tl < 64 + D) {
        const int d = tl - 64;
        float s = 0.0f;
#pragma unroll
        for (int k = 0; k < D; ++k) s = fmaf(xr[k], W1[(D + k) * D + d], s);
        aj[(size_t)r * D + d] = s;
    }

    if (bid == 0 && t < 64) {
        // A = W2^T: A[m=d, k] = W2[k][d]; lane: m = l&15, k = kt*32 + (l>>4)*8 + e
        const int lr = t & 15, lg = t >> 4;
#pragma unroll
        for (int mt = 0; mt < 3; ++mt)
#pragma unroll
            for (int kt = 0; kt < 2; ++kt) {
                unsigned int u[4];
#pragma unroll
                for (int pe = 0; pe < 4; ++pe) {
                    int k0 = kt * 32 + lg * 8 + pe * 2;
                    int dd = mt * 16 + lr;
                    float v0 = (k0 < D && dd < D) ? W2[k0 * D + dd] : 0.0f;
                    float v1 = (k0 + 1 < D && dd < D) ? W2[(k0 + 1) * D + dd] : 0.0f;
                    u[pe] = pk16(v0, v1);
                }
                w2fT[(mt * 2 + kt) * 64 + t] = make_uint4(u[0], u[1], u[2], u[3]);
            }
    }
}

// One block per (bb, row-pair {1023-i1, i1}) -> 1024 equal-work blocks.
// No online max: s <= ~20 so w = e^s is f32-safe (bit-validated R13/R14).
__global__ __launch_bounds__(256)
__attribute__((amdgpu_waves_per_eu(4)))     // min 4 waves/EU -> VGPR budget <= 128
void pair_kernel(
    const float* __restrict__ ai_g, const float* __restrict__ aj_g,
    const uint4* __restrict__ w2fT, const float* __restrict__ b2,
    float* __restrict__ out) {
    __shared__ float mbuf[224];               // 4 waves x 56 (only LDS use)

    const int t = threadIdx.x;
    const int bid = blockIdx.x;
    const int bb = bid & 1;
    const int i1 = bid >> 1;                  // 0..511: rows {NN-1-i1, i1}
    const int w = t >> 6;
    const int l = t & 63;
    const int lr = l & 15;
    const int lg = l >> 4;
    const int idxA = lr << 2;

    // W2^T A-fragments (zero rows for k>=40 kill don't-care B slots), pinned
    f16x8 w2t[3][2];
#pragma unroll
    for (int mt = 0; mt < 3; ++mt)
#pragma unroll
        for (int kt = 0; kt < 2; ++kt) {
            w2t[mt][kt] = __builtin_bit_cast(f16x8, w2fT[(mt * 2 + kt) * 64 + l]);
            pin8(w2t[mt][kt]);
        }

    float bv2[3][4];
#pragma unroll
    for (int mt = 0; mt < 3; ++mt)
#pragma unroll
        for (int r = 0; r < 4; ++r) {
            int d = mt * 16 + lg * 4 + r;
            bv2[mt][r] = (d < D) ? b2[d] : 0.0f;
            pinf(bv2[mt][r]);
        }

    const float* aj_b = aj_g + (size_t)bb * NN * D;

    for (int half = 0; half < 2; ++half) {
        const int i = half ? i1 : (NN - 1 - i1);

        const float* ai_row = ai_g + ((size_t)bb * NN + i) * D;
        float4 air0 = *reinterpret_cast<const float4*>(ai_row + (lg << 3));
        float4 air1 = *reinterpret_cast<const float4*>(ai_row + (lg << 3) + 4);
        float4 ai32 = *reinterpret_cast<const float4*>(ai_row + 32 + ((l >> 5) << 2));
        pin4(air0); pin4(air1); pin4(ai32);

        float l_run = 0.0f;
        float o[3][4];
#pragma unroll
        for (int mt = 0; mt < 3; ++mt)
#pragma unroll
            for (int r = 0; r < 4; ++r) o[mt][r] = 0.0f;

        auto window = [&](int jb, float4 qa0, float4 qa1, float4 qb0,
                          float4 qb1, float4 qt, bool masked) {
            // tail gelu: k = 32+kk..+3 (kk=(l>>5)*4) of j = jb+(l&31)
            unsigned int pd0, pd1;
            {
                float g0 = gelu_tanh(ai32.x + qt.x);
                float g1 = gelu_tanh(ai32.y + qt.y);
                float g2 = gelu_tanh(ai32.z + qt.z);
                float g3 = gelu_tanh(ai32.w + qt.w);
                pd0 = pk16(g0, g1);
                pd1 = pk16(g2, g3);
            }
            uint4 tB0, tB1;
            tB0.x = __builtin_amdgcn_ds_bpermute(idxA,       pd0);
            tB0.y = __builtin_amdgcn_ds_bpermute(idxA,       pd1);
            tB0.z = __builtin_amdgcn_ds_bpermute(idxA + 128, pd0);
            tB0.w = __builtin_amdgcn_ds_bpermute(idxA + 128, pd1);
            tB1.x = __builtin_amdgcn_ds_bpermute(idxA + 64,  pd0);
            tB1.y = __builtin_amdgcn_ds_bpermute(idxA + 64,  pd1);
            tB1.z = __builtin_amdgcn_ds_bpermute(idxA + 192, pd0);
            tB1.w = __builtin_amdgcn_ds_bpermute(idxA + 192, pd1);

            f32x4 acc[3][2];
#pragma unroll
            for (int mt = 0; mt < 3; ++mt)
#pragma unroll
                for (int n = 0; n < 2; ++n)
                    acc[mt][n] = (f32x4){bv2[mt][0], bv2[mt][1], bv2[mt][2], bv2[mt][3]};
            {
                f16x8 B = frag8(air0, air1, qa0, qa1);
                f16x8 Bt = __builtin_bit_cast(f16x8, tB0);
#pragma unroll
                for (int mt = 0; mt < 3; ++mt) {
                    acc[mt][0] = __builtin_amdgcn_mfma_f32_16x16x32_f16(
                        w2t[mt][0], B, acc[mt][0], 0, 0, 0);
                    acc[mt][0] = __builtin_amdgcn_mfma_f32_16x16x32_f16(
                        w2t[mt][1], Bt, acc[mt][0], 0, 0, 0);
                }
            }
            {
                f16x8 B = frag8(air0, air1, qb0, qb1);
                f16x8 Bt = __builtin_bit_cast(f16x8, tB1);
#pragma unroll
                for (int mt = 0; mt < 3; ++mt) {
                    acc[mt][1] = __builtin_amdgcn_mfma_f32_16x16x32_f16(
                        w2t[mt][0], B, acc[mt][1], 0, 0, 0);
                    acc[mt][1] = __builtin_amdgcn_mfma_f32_16x16x32_f16(
                        w2t[mt][1], Bt, acc[mt][1], 0, 0, 0);
                }
            }

            // ||p|| per j; w = e^s directly (no max shift)
            float sv[2];
#pragma unroll
            for (int n = 0; n < 2; ++n) {
                float sq = 0.0f;
#pragma unroll
                for (int mt = 0; mt < 3; ++mt)
#pragma unroll
                    for (int r = 0; r < 4; ++r)
                        sq = fmaf(acc[mt][n][r], acc[mt][n][r], sq);
                sq += __shfl_xor(sq, 16);
                sq += __shfl_xor(sq, 32);
                if (masked) {
                    int j = jb + n * 16 + lr;
                    sv[n] = (j <= i) ? __builtin_amdgcn_sqrtf(sq) : -1e30f;
                } else {
                    sv[n] = __builtin_amdgcn_sqrtf(sq);
                }
            }
            float w0 = __expf(sv[0]);          // masked j -> exactly 0
            float w1 = __expf(sv[1]);
            l_run += w0 + w1;
#pragma unroll
            for (int mt = 0; mt < 3; ++mt)
#pragma unroll
                for (int r = 0; r < 4; ++r)
                    o[mt][r] = fmaf(w0, acc[mt][0][r], fmaf(w1, acc[mt][1][r], o[mt][r]));
        };

        // ---- full windows: induction pointers, fixed-offset loads ----
        int jbase = w << 5;
        const float* pA = aj_b + (size_t)(jbase + lr) * D + (lg << 3);
        const float* pT = aj_b + (size_t)(jbase + (l & 31)) * D + 32 + ((l >> 5) << 2);
        for (; jbase + 31 <= i; jbase += 128) {
            float4 qa0 = *reinterpret_cast<const float4*>(pA);
            float4 qa1 = *reinterpret_cast<const float4*>(pA + 4);
            float4 qb0 = *reinterpret_cast<const float4*>(pA + 16 * D);
            float4 qb1 = *reinterpret_cast<const float4*>(pA + 16 * D + 4);
            float4 qt  = *reinterpret_cast<const float4*>(pT);
            pA += 128 * D;
            pT += 128 * D;
            window(jbase, qa0, qa1, qb0, qb1, qt, false);
        }
        // ---- at most one partial window ----
        if (jbase <= i) {
            const int j0 = min(jbase + lr, i);
            const int j1 = min(jbase + 16 + lr, i);
            const int jt = min(jbase + (l & 31), i);
            const float* r0 = aj_b + (size_t)j0 * D + (lg << 3);
            const float* r1 = aj_b + (size_t)j1 * D + (lg << 3);
            float4 qa0 = *reinterpret_cast<const float4*>(r0);
            float4 qa1 = *reinterpret_cast<const float4*>(r0 + 4);
            float4 qb0 = *reinterpret_cast<const float4*>(r1);
            float4 qb1 = *reinterpret_cast<const float4*>(r1 + 4);
            float4 qt  = *reinterpret_cast<const float4*>(
                aj_b + (size_t)jt * D + 32 + ((l >> 5) << 2));
            window(jbase, qa0, qa1, qb0, qb1, qt, true);
        }

        // ---- epilogue: reduce over 16 j-lanes, merge 4 waves, write row ----
#pragma unroll
        for (int mt = 0; mt < 3; ++mt)
#pragma unroll
            for (int r = 0; r < 4; ++r) {
                float v = o[mt][r];
                v += __shfl_xor(v, 1);
                v += __shfl_xor(v, 2);
                v += __shfl_xor(v, 4);
                v += __shfl_xor(v, 8);
                o[mt][r] = v;
            }
        l_run += __shfl_xor(l_run, 1);
        l_run += __shfl_xor(l_run, 2);
        l_run += __shfl_xor(l_run, 4);
        l_run += __shfl_xor(l_run, 8);

        if (lr == 0) {
#pragma unroll
            for (int mt = 0; mt < 3; ++mt)
#pragma unroll
                for (int r = 0; r < 4; ++r) {
                    int d = mt * 16 + lg * 4 + r;
                    if (d < D) mbuf[w * 56 + d] = o[mt][r];
                }
            if (lg == 0) mbuf[w * 56 + 48] = l_run;
        }
        __syncthreads();
        if (t < D) {
            float L = mbuf[48] + mbuf[56 + 48] + mbuf[112 + 48] + mbuf[168 + 48];
            float val = mbuf[t] + mbuf[56 + t] + mbuf[112 + t] + mbuf[168 + t];
            out[((size_t)bb * NN + i) * D + t] = val / L;
        }
        __syncthreads();   // mbuf reads done before next half overwrites
    }
}

extern "C" void kernel_launch(void* const* d_in, const int* in_sizes, int n_in,
                              void* d_out, int out_size, void* d_ws, size_t ws_size,
                              hipStream_t stream) {
    const float* x  = (const float*)d_in[0];
    const float* W1 = (const float*)d_in[1];
    const float* b1 = (const float*)d_in[2];
    const float* W2 = (const float*)d_in[3];
    const float* b2 = (const float*)d_in[4];
    float* out = (float*)d_out;

    float* ai = (float*)d_ws;                          // BB*NN*D floats
    float* aj = ai + (size_t)BB * NN * D;              // BB*NN*D floats
    uint4* w2fT = (uint4*)(aj + (size_t)BB * NN * D);  // 384 uint4

    precompute_kernel<<<BB * NN / 2, 256, 0, stream>>>(x, W1, b1, W2, ai, aj, w2fT);
    pair_kernel<<<BB * NN / 2, 256, 0, stream>>>(ai, aj, w2fT, b2, out);
}

// Round 16
// 32.872 us; speedup vs baseline: 1.8218x; 1.1403x over previous
//
#include <hip/hip_runtime.h>
#include <math.h>

#define D 40
#define NN 1024
#define BB 2

typedef __attribute__((ext_vector_type(8))) _Float16 f16x8;
typedef __attribute__((ext_vector_type(4))) float f32x4;

__device__ __forceinline__ unsigned int pk16(float a, float b) {
    return __builtin_bit_cast(unsigned int, __builtin_amdgcn_cvt_pkrtz(a, b));
}

// gelu = a - a/(exp2(a*(c1*a^2+c0))+1); 5 VALU + 2 trans
__device__ __forceinline__ float gelu_tanh(float a) {
    float u = a * a;
    float t1 = fmaf(0.10294366f, u, 2.3022083f);
    float e = __builtin_amdgcn_exp2f(a * t1);
    float r = __builtin_amdgcn_rcpf(e + 1.0f);
    return fmaf(-a, r, a);
}

// anti-remat pins
__device__ __forceinline__ void pinf(float& x) { asm volatile("" : "+v"(x)); }
__device__ __forceinline__ void pin4(float4& v) {
    asm volatile("" : "+v"(v.x), "+v"(v.y), "+v"(v.z), "+v"(v.w));
}
__device__ __forceinline__ void pin8(f16x8& v) {
    uint4 u = __builtin_bit_cast(uint4, v);
    asm volatile("" : "+v"(u.x), "+v"(u.y), "+v"(u.z), "+v"(u.w));
    v = __builtin_bit_cast(f16x8, u);
}

// build fp16x8 B-fragment: gelu(air + ajv) for 8 consecutive k
__device__ __forceinline__ f16x8 frag8(float4 a0, float4 a1, float4 x0, float4 x1) {
    float g0 = gelu_tanh(a0.x + x0.x);
    float g1 = gelu_tanh(a0.y + x0.y);
    float g2 = gelu_tanh(a0.z + x0.z);
    float g3 = gelu_tanh(a0.w + x0.w);
    float g4 = gelu_tanh(a1.x + x1.x);
    float g5 = gelu_tanh(a1.y + x1.y);
    float g6 = gelu_tanh(a1.z + x1.z);
    float g7 = gelu_tanh(a1.w + x1.w);
    return __builtin_bit_cast(f16x8,
        make_uint4(pk16(g0, g1), pk16(g2, g3), pk16(g4, g5), pk16(g6, g7)));
}

// ai = x @ W1[:D] + b1, aj = x @ W1[D:].  2 rows/block; one 40-FMA chain/thread.
__global__ __launch_bounds__(256) void precompute_kernel(
    const float* __restrict__ x, const float* __restrict__ W1,
    const float* __restrict__ b1, const float* __restrict__ W2,
    float* __restrict__ ai, float* __restrict__ aj, uint4* __restrict__ w2fT) {
    const int t = threadIdx.x;
    const int bid = blockIdx.x;
    const int r = (bid << 1) + (t >> 7);
    const int tl = t & 127;
    const float* xr = x + (size_t)r * D;

    if (tl < D) {
        const int d = tl;
        float s = b1[d];
#pragma unroll
        for (int k = 0; k < D; ++k) s = fmaf(xr[k], W1[k * D + d], s);
        ai[(size_t)r * D + d] = s;
    } else if (tl >= 64 && tl < 64 + D) {
        const int d = tl - 64;
        float s = 0.0f;
#pragma unroll
        for (int k = 0; k < D; ++k) s = fmaf(xr[k], W1[(D + k) * D + d], s);
        aj[(size_t)r * D + d] = s;
    }

    if (bid == 0 && t < 64) {
        // A = W2^T: A[m=d, k] = W2[k][d]; lane: m = l&15, k = kt*32 + (l>>4)*8 + e
        const int lr = t & 15, lg = t >> 4;
#pragma unroll
        for (int mt = 0; mt < 3; ++mt)
#pragma unroll
            for (int kt = 0; kt < 2; ++kt) {
                unsigned int u[4];
#pragma unroll
                for (int pe = 0; pe < 4; ++pe) {
                    int k0 = kt * 32 + lg * 8 + pe * 2;
                    int dd = mt * 16 + lr;
                    float v0 = (k0 < D && dd < D) ? W2[k0 * D + dd] : 0.0f;
                    float v1 = (k0 + 1 < D && dd < D) ? W2[(k0 + 1) * D + dd] : 0.0f;
                    u[pe] = pk16(v0, v1);
                }
                w2fT[(mt * 2 + kt) * 64 + t] = make_uint4(u[0], u[1], u[2], u[3]);
            }
    }
}

__global__ __launch_bounds__(256)
__attribute__((amdgpu_waves_per_eu(4)))     // min 4 waves/EU -> VGPR budget <= 128
void pair_kernel(
    const float* __restrict__ ai_g, const float* __restrict__ aj_g,
    const uint4* __restrict__ w2fT, const float* __restrict__ b2,
    float* __restrict__ out) {
    __shared__ float mbuf[224];               // 4 waves x 56 (only LDS use)

    const int t = threadIdx.x;
    const int bid = blockIdx.x;
    const int bb = bid & 1;
    const int i = NN - 1 - (bid >> 1);        // big rows first
    const int w = t >> 6;
    const int l = t & 63;
    const int lr = l & 15;
    const int lg = l >> 4;                    // 0..3
    const int idxA = lr << 2;

    // W2^T A-fragments (zero rows for k>=40 kill don't-care B slots), pinned
    f16x8 w2t[3][2];
#pragma unroll
    for (int mt = 0; mt < 3; ++mt)
#pragma unroll
        for (int kt = 0; kt < 2; ++kt) {
            w2t[mt][kt] = __builtin_bit_cast(f16x8, w2fT[(mt * 2 + kt) * 64 + l]);
            pin8(w2t[mt][kt]);
        }

    // bias for d = mt*16 + lg*4 + r (0 for d >= 40), pinned
    float bv2[3][4];
#pragma unroll
    for (int mt = 0; mt < 3; ++mt)
#pragma unroll
        for (int r = 0; r < 4; ++r) {
            int d = mt * 16 + lg * 4 + r;
            bv2[mt][r] = (d < D) ? b2[d] : 0.0f;
            pinf(bv2[mt][r]);
        }

    const float* ai_row = ai_g + ((size_t)bb * NN + i) * D;
    float4 air0 = *reinterpret_cast<const float4*>(ai_row + (lg << 3));
    float4 air1 = *reinterpret_cast<const float4*>(ai_row + (lg << 3) + 4);
    float4 ai32 = *reinterpret_cast<const float4*>(ai_row + 32 + ((l >> 5) << 2));
    pin4(air0); pin4(air1); pin4(ai32);

    const float* aj_b = aj_g + (size_t)bb * NN * D;

    // no-max softmax state: s <= ~20 so w = e^s is f32-safe (bit-validated R13-R15)
    float l_run = 0.0f;
    float o[3][4];
#pragma unroll
    for (int mt = 0; mt < 3; ++mt)
#pragma unroll
        for (int r = 0; r < 4; ++r) o[mt][r] = 0.0f;

    auto window = [&](int jbase, float4 qa0, float4 qa1, float4 qb0,
                      float4 qb1, float4 qt, bool masked) {
        // tail gelu: k = 32+kk..+3 (kk=(l>>5)*4) of j = jbase+(l&31)
        unsigned int pd0, pd1;
        {
            float g0 = gelu_tanh(ai32.x + qt.x);
            float g1 = gelu_tanh(ai32.y + qt.y);
            float g2 = gelu_tanh(ai32.z + qt.z);
            float g3 = gelu_tanh(ai32.w + qt.w);
            pd0 = pk16(g0, g1);
            pd1 = pk16(g2, g3);
        }
        uint4 tB0, tB1;
        tB0.x = __builtin_amdgcn_ds_bpermute(idxA,       pd0);
        tB0.y = __builtin_amdgcn_ds_bpermute(idxA,       pd1);
        tB0.z = __builtin_amdgcn_ds_bpermute(idxA + 128, pd0);
        tB0.w = __builtin_amdgcn_ds_bpermute(idxA + 128, pd1);
        tB1.x = __builtin_amdgcn_ds_bpermute(idxA + 64,  pd0);
        tB1.y = __builtin_amdgcn_ds_bpermute(idxA + 64,  pd1);
        tB1.z = __builtin_amdgcn_ds_bpermute(idxA + 192, pd0);
        tB1.w = __builtin_amdgcn_ds_bpermute(idxA + 192, pd1);

        f32x4 acc[3][2];
#pragma unroll
        for (int mt = 0; mt < 3; ++mt)
#pragma unroll
            for (int n = 0; n < 2; ++n)
                acc[mt][n] = (f32x4){bv2[mt][0], bv2[mt][1], bv2[mt][2], bv2[mt][3]};
        {
            f16x8 B = frag8(air0, air1, qa0, qa1);
            f16x8 Bt = __builtin_bit_cast(f16x8, tB0);
#pragma unroll
            for (int mt = 0; mt < 3; ++mt) {
                acc[mt][0] = __builtin_amdgcn_mfma_f32_16x16x32_f16(
                    w2t[mt][0], B, acc[mt][0], 0, 0, 0);
                acc[mt][0] = __builtin_amdgcn_mfma_f32_16x16x32_f16(
                    w2t[mt][1], Bt, acc[mt][0], 0, 0, 0);
            }
        }
        {
            f16x8 B = frag8(air0, air1, qb0, qb1);
            f16x8 Bt = __builtin_bit_cast(f16x8, tB1);
#pragma unroll
            for (int mt = 0; mt < 3; ++mt) {
                acc[mt][1] = __builtin_amdgcn_mfma_f32_16x16x32_f16(
                    w2t[mt][0], B, acc[mt][1], 0, 0, 0);
                acc[mt][1] = __builtin_amdgcn_mfma_f32_16x16x32_f16(
                    w2t[mt][1], Bt, acc[mt][1], 0, 0, 0);
            }
        }

        // ||p|| per j; w = e^s directly (no max shift, no rescale)
        float sv[2];
#pragma unroll
        for (int n = 0; n < 2; ++n) {
            float sq = 0.0f;
#pragma unroll
            for (int mt = 0; mt < 3; ++mt)
#pragma unroll
                for (int r = 0; r < 4; ++r)
                    sq = fmaf(acc[mt][n][r], acc[mt][n][r], sq);
            sq += __shfl_xor(sq, 16);
            sq += __shfl_xor(sq, 32);
            if (masked) {
                int j = jbase + n * 16 + lr;
                sv[n] = (j <= i) ? __builtin_amdgcn_sqrtf(sq) : -1e30f;
            } else {
                sv[n] = __builtin_amdgcn_sqrtf(sq);
            }
        }
        float w0 = __expf(sv[0]);              // masked j -> exactly 0
        float w1 = __expf(sv[1]);
        l_run += w0 + w1;
#pragma unroll
        for (int mt = 0; mt < 3; ++mt)
#pragma unroll
            for (int r = 0; r < 4; ++r)
                o[mt][r] = fmaf(w0, acc[mt][0][r], fmaf(w1, acc[mt][1][r], o[mt][r]));
    };

    // ---- full windows: no clamps, induction pointers, fixed-offset loads ----
    int jbase = w << 5;
    const float* pA = aj_b + (size_t)(jbase + lr) * D + (lg << 3);
    const float* pT = aj_b + (size_t)(jbase + (l & 31)) * D + 32 + ((l >> 5) << 2);
    for (; jbase + 31 <= i; jbase += 128) {
        float4 qa0 = *reinterpret_cast<const float4*>(pA);
        float4 qa1 = *reinterpret_cast<const float4*>(pA + 4);
        float4 qb0 = *reinterpret_cast<const float4*>(pA + 16 * D);
        float4 qb1 = *reinterpret_cast<const float4*>(pA + 16 * D + 4);
        float4 qt  = *reinterpret_cast<const float4*>(pT);
        pA += 128 * D;
        pT += 128 * D;
        window(jbase, qa0, qa1, qb0, qb1, qt, false);
    }
    // ---- at most one partial window (clamped loads, masked sv) ----
    if (jbase <= i) {
        const int j0 = min(jbase + lr, i);
        const int j1 = min(jbase + 16 + lr, i);
        const int jt = min(jbase + (l & 31), i);
        const float* r0 = aj_b + (size_t)j0 * D + (lg << 3);
        const float* r1 = aj_b + (size_t)j1 * D + (lg << 3);
        float4 qa0 = *reinterpret_cast<const float4*>(r0);
        float4 qa1 = *reinterpret_cast<const float4*>(r0 + 4);
        float4 qb0 = *reinterpret_cast<const float4*>(r1);
        float4 qb1 = *reinterpret_cast<const float4*>(r1 + 4);
        float4 qt  = *reinterpret_cast<const float4*>(
            aj_b + (size_t)jt * D + 32 + ((l >> 5) << 2));
        window(jbase, qa0, qa1, qb0, qb1, qt, true);
    }

    // ---- reduce o over the 16 j-lanes, merge 4 waves ----
#pragma unroll
    for (int mt = 0; mt < 3; ++mt)
#pragma unroll
        for (int r = 0; r < 4; ++r) {
            float v = o[mt][r];
            v += __shfl_xor(v, 1);
            v += __shfl_xor(v, 2);
            v += __shfl_xor(v, 4);
            v += __shfl_xor(v, 8);
            o[mt][r] = v;
        }
    l_run += __shfl_xor(l_run, 1);
    l_run += __shfl_xor(l_run, 2);
    l_run += __shfl_xor(l_run, 4);
    l_run += __shfl_xor(l_run, 8);

    if (lr == 0) {
#pragma unroll
        for (int mt = 0; mt < 3; ++mt)
#pragma unroll
            for (int r = 0; r < 4; ++r) {
                int d = mt * 16 + lg * 4 + r;
                if (d < D) mbuf[w * 56 + d] = o[mt][r];
            }
        if (lg == 0) mbuf[w * 56 + 48] = l_run;
    }
    __syncthreads();
    if (t < D) {
        float L = mbuf[48] + mbuf[56 + 48] + mbuf[112 + 48] + mbuf[168 + 48];
        float val = mbuf[t] + mbuf[56 + t] + mbuf[112 + t] + mbuf[168 + t];
        out[((size_t)bb * NN + i) * D + t] = val / L;
    }
}

extern "C" void kernel_launch(void* const* d_in, const int* in_sizes, int n_in,
                              void* d_out, int out_size, void* d_ws, size_t ws_size,
                              hipStream_t stream) {
    const float* x  = (const float*)d_in[0];
    const float* W1 = (const float*)d_in[1];
    const float* b1 = (const float*)d_in[2];
    const float* W2 = (const float*)d_in[3];
    const float* b2 = (const float*)d_in[4];
    float* out = (float*)d_out;

    float* ai = (float*)d_ws;                          // BB*NN*D floats
    float* aj = ai + (size_t)BB * NN * D;              // BB*NN*D floats
    uint4* w2fT = (uint4*)(aj + (size_t)BB * NN * D);  // 384 uint4

    precompute_kernel<<<BB * NN / 2, 256, 0, stream>>>(x, W1, b1, W2, ai, aj, w2fT);
    pair_kernel<<<BB * NN, 256, 0, stream>>>(ai, aj, w2fT, b2, out);
}